// Round 2
// baseline (744.177 us; speedup 1.0000x reference)
//
#include <hip/hip_runtime.h>

#define NN 30000
#define NE 300000
#define HIDDEN 256

typedef __attribute__((ext_vector_type(8))) __bf16 bf16x8;
typedef __attribute__((ext_vector_type(4))) __bf16 bf16x4;
typedef __attribute__((ext_vector_type(4))) float float4v;

__device__ inline __bf16 f2bf(float f) {
  unsigned u = __builtin_bit_cast(unsigned, f);
  u += 0x7fffu + ((u >> 16) & 1u);
  unsigned short s = (unsigned short)(u >> 16);
  return __builtin_bit_cast(__bf16, s);
}
__device__ inline float bf2f(__bf16 b) {
  unsigned short s = __builtin_bit_cast(unsigned short, b);
  unsigned u = ((unsigned)s) << 16;
  return __builtin_bit_cast(float, u);
}
__device__ inline float gelu_tanh(float x) {
  float x3 = x * x * x;
  return 0.5f * x * (1.0f + tanhf(0.79788456080286536f * (x + 0.044715f * x3)));
}

// ---------------- prep kernels ----------------
__global__ void zero_int_kernel(int* __restrict__ p, int n) {
  int i = blockIdx.x * 256 + threadIdx.x;
  if (i < n) p[i] = 0;
}

// Wqe[D][h*32+d] = sum_c Wq[D][h*32+c] * We[d][h*32+c]   (all fp32)
__global__ void wqe_kernel(const float* __restrict__ Wq, const float* __restrict__ We,
                           float* __restrict__ Wqe) {
  int idx = blockIdx.x * 256 + threadIdx.x;
  if (idx >= 256 * 256) return;
  int D = idx >> 8, col = idx & 255;
  int h = col >> 5, d = col & 31;
  const float* wq = Wq + (size_t)D * 256 + h * 32;
  const float* we = We + (size_t)d * 256 + h * 32;
  float s = 0.f;
#pragma unroll
  for (int c = 0; c < 32; ++c) s += wq[c] * we[c];
  Wqe[idx] = s;
}

// ball = [bq | bk | bv | bqe],  bqe[h*32+d] = sum_c bq[h*32+c]*We[d][h*32+c]
__global__ void ball_kernel(const float* __restrict__ bq, const float* __restrict__ bk,
                            const float* __restrict__ bv, const float* __restrict__ We,
                            float* __restrict__ ball) {
  int j = blockIdx.x * 256 + threadIdx.x;
  if (j >= 1024) return;
  float v;
  if (j < 256) v = bq[j];
  else if (j < 512) v = bk[j - 256];
  else if (j < 768) v = bv[j - 512];
  else {
    int col = j - 768, h = col >> 5, d = col & 31;
    const float* bqh = bq + h * 32;
    const float* we = We + (size_t)d * 256 + h * 32;
    float s = 0.f;
#pragma unroll
    for (int c = 0; c < 32; ++c) s += bqh[c] * we[c];
    v = s;
  }
  ball[j] = v;
}

// WeT[ch][d] = We[d][ch]  (fp32, 256x32)
__global__ void wet_kernel(const float* __restrict__ We, float* __restrict__ WeT) {
  int idx = blockIdx.x * 256 + threadIdx.x;
  if (idx >= 256 * 32) return;
  int ch = idx >> 5, d = idx & 31;
  WeT[idx] = We[(size_t)d * 256 + ch];
}

// Wt[n][k] (bf16) = W[k][Nout=256][n]  transpose+cast; K=256
__global__ void transpose_w_kernel(const float* __restrict__ W, __bf16* __restrict__ Wt) {
  int idx = blockIdx.x * 256 + threadIdx.x;
  if (idx >= 256 * 256) return;
  int k = idx & 255, n = idx >> 8;
  Wt[idx] = f2bf(W[(size_t)k * 256 + n]);
}

// ---------------- CSR build ----------------
__global__ void count_deg_kernel(const int* __restrict__ dst, int* __restrict__ deg, int E) {
  int e = blockIdx.x * 256 + threadIdx.x;
  if (e < E) atomicAdd(&deg[dst[e]], 1);
}

__global__ __launch_bounds__(1024) void scan_kernel(const int* __restrict__ deg,
                                                    int* __restrict__ offs, int n) {
  __shared__ int part[1024];
  const int tid = threadIdx.x;
  const int per = (n + 1023) / 1024;
  const int base = tid * per;
  int s = 0;
  for (int j = 0; j < per; ++j) {
    int i = base + j;
    if (i < n) s += deg[i];
  }
  part[tid] = s;
  __syncthreads();
  for (int st = 1; st < 1024; st <<= 1) {
    int t = (tid >= st) ? part[tid - st] : 0;
    __syncthreads();
    part[tid] += t;
    __syncthreads();
  }
  int run = (tid > 0) ? part[tid - 1] : 0;
  for (int j = 0; j < per; ++j) {
    int i = base + j;
    if (i < n) { offs[i] = run; run += deg[i]; }
  }
  if (tid == 1023) offs[n] = part[1023];
}

__global__ void scatter_kernel(const int* __restrict__ srcIn, const int* __restrict__ dstIn,
                               const int* __restrict__ offs, int* __restrict__ cursor,
                               int* __restrict__ srcs, int* __restrict__ eids, int E) {
  int e = blockIdx.x * 256 + threadIdx.x;
  if (e >= E) return;
  int d = dstIn[e];
  int p = atomicAdd(&cursor[d], 1);
  int o = offs[d] + p;
  srcs[o] = srcIn[e];
  eids[o] = e;
}

// ---------------- MFMA GEMM ----------------
// Y[M][NSTR] = epi(A[M][256] @ W[256][NSTR] + bias); Wt = W^T bf16 [NSTR][256].
// EPI: 0 = (+bias) store bf16; 1 = (+bias) store fp32;
//      2 = +bias, gelu, store bf16; 3 = +bias, gelu, +resid, store fp32
template <int NSTR, bool ABF, int EPI>
__global__ __launch_bounds__(256) void gemm_k(
    const float* __restrict__ Af, const __bf16* __restrict__ Abf,
    const __bf16* __restrict__ Wt, const float* __restrict__ bias,
    float* __restrict__ Yf, __bf16* __restrict__ Ybf,
    const float* __restrict__ resid, int M) {
  const int lane = threadIdx.x & 63;
  const int wave = threadIdx.x >> 6;
  const int r = lane & 15;
  const int q = lane >> 4;
  const int n0 = blockIdx.x * 64;
  const int m0 = blockIdx.y * 64 + wave * 16;
  int arow = m0 + r;
  if (arow >= M) arow = M - 1;

  float4v acc0 = {0.f, 0.f, 0.f, 0.f};
  float4v acc1 = acc0, acc2 = acc0, acc3 = acc0;
  const int kq = q * 8;

#pragma unroll
  for (int kk = 0; kk < 256; kk += 32) {
    const int ka = kk + kq;
    bf16x8 af;
    if constexpr (ABF) {
      af = *(const bf16x8*)(Abf + (size_t)arow * 256 + ka);
    } else {
      const float* ap = Af + (size_t)arow * 256 + ka;
      float4v f0 = *(const float4v*)(ap);
      float4v f1 = *(const float4v*)(ap + 4);
      af[0] = f2bf(f0[0]); af[1] = f2bf(f0[1]); af[2] = f2bf(f0[2]); af[3] = f2bf(f0[3]);
      af[4] = f2bf(f1[0]); af[5] = f2bf(f1[1]); af[6] = f2bf(f1[2]); af[7] = f2bf(f1[3]);
    }
    bf16x8 bw0 = *(const bf16x8*)(Wt + (size_t)(n0 + 0 + r) * 256 + ka);
    bf16x8 bw1 = *(const bf16x8*)(Wt + (size_t)(n0 + 16 + r) * 256 + ka);
    bf16x8 bw2 = *(const bf16x8*)(Wt + (size_t)(n0 + 32 + r) * 256 + ka);
    bf16x8 bw3 = *(const bf16x8*)(Wt + (size_t)(n0 + 48 + r) * 256 + ka);
    acc0 = __builtin_amdgcn_mfma_f32_16x16x32_bf16(af, bw0, acc0, 0, 0, 0);
    acc1 = __builtin_amdgcn_mfma_f32_16x16x32_bf16(af, bw1, acc1, 0, 0, 0);
    acc2 = __builtin_amdgcn_mfma_f32_16x16x32_bf16(af, bw2, acc2, 0, 0, 0);
    acc3 = __builtin_amdgcn_mfma_f32_16x16x32_bf16(af, bw3, acc3, 0, 0, 0);
  }

  float4v accs[4] = {acc0, acc1, acc2, acc3};
#pragma unroll
  for (int t = 0; t < 4; ++t) {
    const int col = n0 + t * 16 + r;
    const float b = bias ? bias[col] : 0.0f;
#pragma unroll
    for (int i = 0; i < 4; ++i) {
      const int row = m0 + q * 4 + i;
      if (row < M) {
        float v = accs[t][i] + b;
        if constexpr (EPI == 2 || EPI == 3) v = gelu_tanh(v);
        const size_t off = (size_t)row * NSTR + col;
        if constexpr (EPI == 3) v += resid[off];
        if constexpr (EPI == 1 || EPI == 3) Yf[off] = v;
        else Ybf[off] = f2bf(v);
      }
    }
  }
}

// ---------------- attention ----------------
// QKVQE row layout: [q(256) | k(256) | v(256) | qe(256)], stride 1024, bf16.
// One wave per dst node; lane owns channels c0=lane*4 (head hg=lane>>3) and
// edge-dims d0=(lane&7)*4 of its head. OUT (fp32) is RMW'd (+= agg_v);
// AE (bf16) gets sum(alpha*ea)/denom for the post kernel.
__global__ __launch_bounds__(256) void attn_kernel(
    const __bf16* __restrict__ QKVQE, const float* __restrict__ ea,
    const int* __restrict__ offs, const int* __restrict__ srcs, const int* __restrict__ eids,
    float* __restrict__ OUT, __bf16* __restrict__ AE) {
  const int lane = threadIdx.x & 63;
  const int wave = threadIdx.x >> 6;
  const int n = blockIdx.x * 4 + wave;
  const int c0 = lane * 4;
  const int sub = lane & 7;

  const __bf16* qrow = QKVQE + (size_t)n * 1024;
  const bf16x4 q4 = *(const bf16x4*)(qrow + c0);
  const bf16x4 g4 = *(const bf16x4*)(qrow + 768 + c0);
  const float q0 = bf2f(q4[0]), q1 = bf2f(q4[1]), q2 = bf2f(q4[2]), q3 = bf2f(q4[3]);
  const float g0 = bf2f(g4[0]), g1 = bf2f(g4[1]), g2 = bf2f(g4[2]), g3 = bf2f(g4[3]);

  float m = -__builtin_inff();
  float denom = 0.f;
  float4v accv = {0.f, 0.f, 0.f, 0.f};
  float4v acce = {0.f, 0.f, 0.f, 0.f};
  const int beg = offs[n], end = offs[n + 1];
  for (int i = beg; i < end; ++i) {
    const int sn = srcs[i];
    const int e = eids[i];
    const __bf16* krow = QKVQE + (size_t)sn * 1024 + 256;
    const bf16x4 k4 = *(const bf16x4*)(krow + c0);
    const bf16x4 v4 = *(const bf16x4*)(krow + 256 + c0);
    const float4v ea4 = *(const float4v*)(ea + (size_t)e * 32 + sub * 4);
    float part = q0 * bf2f(k4[0]) + q1 * bf2f(k4[1]) + q2 * bf2f(k4[2]) + q3 * bf2f(k4[3])
               + g0 * ea4[0] + g1 * ea4[1] + g2 * ea4[2] + g3 * ea4[3];
    part += __shfl_xor(part, 1);
    part += __shfl_xor(part, 2);
    part += __shfl_xor(part, 4);  // full per-head logit in all 8 lanes of the group
    const float logit = part * 0.17677669529663687f;  // 1/sqrt(32)
    const float mn = fmaxf(m, logit);
    const float sc = __expf(m - mn);
    const float w = __expf(logit - mn);
    denom = denom * sc + w;
    accv[0] = accv[0] * sc + w * bf2f(v4[0]);
    accv[1] = accv[1] * sc + w * bf2f(v4[1]);
    accv[2] = accv[2] * sc + w * bf2f(v4[2]);
    accv[3] = accv[3] * sc + w * bf2f(v4[3]);
    acce[0] = acce[0] * sc + w * ea4[0];
    acce[1] = acce[1] * sc + w * ea4[1];
    acce[2] = acce[2] * sc + w * ea4[2];
    acce[3] = acce[3] * sc + w * ea4[3];
    m = mn;
  }
  const float inv = 1.0f / (denom + 1e-16f);
  float4v o = *(const float4v*)(OUT + (size_t)n * HIDDEN + c0);
  o[0] += accv[0] * inv;
  o[1] += accv[1] * inv;
  o[2] += accv[2] * inv;
  o[3] += accv[3] * inv;
  *(float4v*)(OUT + (size_t)n * HIDDEN + c0) = o;
  bf16x4 ae;
  ae[0] = f2bf(acce[0] * inv); ae[1] = f2bf(acce[1] * inv);
  ae[2] = f2bf(acce[2] * inv); ae[3] = f2bf(acce[3] * inv);
  *(bf16x4*)(AE + (size_t)n * HIDDEN + c0) = ae;
}

// ---------------- post: OUT += (AE @ We) per head; write bf16 copy ----------------
__global__ __launch_bounds__(256) void post_kernel(
    const __bf16* __restrict__ AE, const float* __restrict__ WeT,
    float* __restrict__ OUT, __bf16* __restrict__ OUTh) {
  const int lane = threadIdx.x & 63;
  const int wave = threadIdx.x >> 6;
  const int n = blockIdx.x * 4 + wave;
  const int c0 = lane * 4;
  const int hg = lane >> 3;

  const __bf16* aerow = AE + (size_t)n * HIDDEN + hg * 32;
  float ae[32];
#pragma unroll
  for (int t = 0; t < 4; ++t) {
    bf16x8 a8 = *(const bf16x8*)(aerow + t * 8);
#pragma unroll
    for (int j = 0; j < 8; ++j) ae[t * 8 + j] = bf2f(a8[j]);
  }
  float4v o = *(const float4v*)(OUT + (size_t)n * HIDDEN + c0);
#pragma unroll
  for (int j = 0; j < 4; ++j) {
    const float* wc = WeT + (size_t)(c0 + j) * 32;
    float s = 0.f;
#pragma unroll
    for (int d = 0; d < 32; ++d) s += ae[d] * wc[d];
    o[j] += s;
  }
  *(float4v*)(OUT + (size_t)n * HIDDEN + c0) = o;
  bf16x4 ob;
  ob[0] = f2bf(o[0]); ob[1] = f2bf(o[1]); ob[2] = f2bf(o[2]); ob[3] = f2bf(o[3]);
  *(bf16x4*)(OUTh + (size_t)n * HIDDEN + c0) = ob;
}

extern "C" void kernel_launch(void* const* d_in, const int* in_sizes, int n_in,
                              void* d_out, int out_size, void* d_ws, size_t ws_size,
                              hipStream_t stream) {
  (void)in_sizes; (void)n_in; (void)out_size; (void)ws_size;
  const float* x   = (const float*)d_in[0];
  const int*   ei  = (const int*)d_in[1];
  const float* ea  = (const float*)d_in[2];
  const float* Wq  = (const float*)d_in[3];
  const float* bq  = (const float*)d_in[4];
  const float* Wk  = (const float*)d_in[5];
  const float* bk  = (const float*)d_in[6];
  const float* Wv  = (const float*)d_in[7];
  const float* bv  = (const float*)d_in[8];
  const float* We  = (const float*)d_in[9];
  const float* Wsk = (const float*)d_in[10];
  const float* W1  = (const float*)d_in[11];
  const float* b1  = (const float*)d_in[12];
  const float* W2  = (const float*)d_in[13];
  const float* b2  = (const float*)d_in[14];
  float* out = (float*)d_out;

  char* ws = (char*)d_ws;
  size_t off = 0;
  auto alloc = [&](size_t bytes) -> char* {
    off = (off + 255) & ~(size_t)255;
    char* p = ws + off;
    off += bytes;
    return p;
  };
  // ~96 MB total (stay well inside ws_size)
  __bf16* QKVQE = (__bf16*)alloc((size_t)NN * 1024 * 2);   // 61.44 MB
  __bf16* AE    = (__bf16*)alloc((size_t)NN * HIDDEN * 2); // 15.36 MB
  __bf16* OUTh  = (__bf16*)alloc((size_t)NN * HIDDEN * 2); // 15.36 MB
  __bf16* H1    = AE;  // reuse: AE dead after post_kernel, H1 born after
  __bf16* WTall = (__bf16*)alloc((size_t)1024 * 256 * 2);
  __bf16* WTs   = (__bf16*)alloc(256 * 256 * 2);
  __bf16* WT1   = (__bf16*)alloc(256 * 256 * 2);
  __bf16* WT2   = (__bf16*)alloc(256 * 256 * 2);
  float*  Wqe   = (float*)alloc(256 * 256 * 4);
  float*  ball  = (float*)alloc(1024 * 4);
  float*  WeT   = (float*)alloc(256 * 32 * 4);
  int* deg    = (int*)alloc((size_t)2 * NN * 4);  // deg + cursor contiguous
  int* cursor = deg + NN;
  int* offs   = (int*)alloc((size_t)(NN + 1) * 4);
  int* srcs   = (int*)alloc((size_t)NE * 4);
  int* eids   = (int*)alloc((size_t)NE * 4);

  const int* srcIn = ei;       // edge_index[0]
  const int* dstIn = ei + NE;  // edge_index[1]

  // ---- weight prep ----
  wqe_kernel<<<256, 256, 0, stream>>>(Wq, We, Wqe);
  ball_kernel<<<4, 256, 0, stream>>>(bq, bk, bv, We, ball);
  wet_kernel<<<32, 256, 0, stream>>>(We, WeT);
  transpose_w_kernel<<<256, 256, 0, stream>>>(Wq, WTall);
  transpose_w_kernel<<<256, 256, 0, stream>>>(Wk, WTall + 256 * 256);
  transpose_w_kernel<<<256, 256, 0, stream>>>(Wv, WTall + 2 * 256 * 256);
  transpose_w_kernel<<<256, 256, 0, stream>>>(Wqe, WTall + 3 * 256 * 256);
  transpose_w_kernel<<<256, 256, 0, stream>>>(Wsk, WTs);
  transpose_w_kernel<<<256, 256, 0, stream>>>(W1, WT1);
  transpose_w_kernel<<<256, 256, 0, stream>>>(W2, WT2);

  // ---- CSR build ----
  zero_int_kernel<<<(2 * NN + 255) / 256, 256, 0, stream>>>(deg, 2 * NN);
  count_deg_kernel<<<(NE + 255) / 256, 256, 0, stream>>>(dstIn, deg, NE);
  scan_kernel<<<1, 1024, 0, stream>>>(deg, offs, NN);
  scatter_kernel<<<(NE + 255) / 256, 256, 0, stream>>>(srcIn, dstIn, offs, cursor, srcs, eids, NE);

  // ---- fused node GEMM: x @ [Wq|Wk|Wv|Wqe] + [bq|bk|bv|bqe] -> bf16 ----
  dim3 gQ(16, (NN + 63) / 64);
  gemm_k<1024, false, 0><<<gQ, 256, 0, stream>>>(x, nullptr, WTall, ball, nullptr, QKVQE, nullptr, NN);

  // ---- skip GEMM: d_out = x @ Wskip (fp32) ----
  dim3 gN(4, (NN + 63) / 64);
  gemm_k<256, false, 1><<<gN, 256, 0, stream>>>(x, nullptr, WTs, nullptr, out, nullptr, nullptr, NN);

  // ---- attention (RMW d_out, write AE) ----
  attn_kernel<<<NN / 4, 256, 0, stream>>>(QKVQE, ea, offs, srcs, eids, out, AE);

  // ---- post: d_out += AE @ We (block-diag), OUTh = bf16(d_out) ----
  post_kernel<<<NN / 4, 256, 0, stream>>>(AE, WeT, out, OUTh);

  // ---- MLP ----
  gemm_k<256, true, 2><<<gN, 256, 0, stream>>>(nullptr, OUTh, WT1, b1, nullptr, H1, nullptr, NN);
  gemm_k<256, true, 3><<<gN, 256, 0, stream>>>(nullptr, H1, WT2, b2, out, nullptr, out, NN);
}

// Round 3
// 706.571 us; speedup vs baseline: 1.0532x; 1.0532x over previous
//
#include <hip/hip_runtime.h>

#define NN 30000
#define NE 300000
#define HIDDEN 256

typedef __attribute__((ext_vector_type(8))) __bf16 bf16x8;
typedef __attribute__((ext_vector_type(4))) __bf16 bf16x4;
typedef __attribute__((ext_vector_type(4))) float float4v;

__device__ inline __bf16 f2bf(float f) {
  unsigned u = __builtin_bit_cast(unsigned, f);
  u += 0x7fffu + ((u >> 16) & 1u);
  unsigned short s = (unsigned short)(u >> 16);
  return __builtin_bit_cast(__bf16, s);
}
__device__ inline float bf2f(__bf16 b) {
  unsigned short s = __builtin_bit_cast(unsigned short, b);
  unsigned u = ((unsigned)s) << 16;
  return __builtin_bit_cast(float, u);
}
__device__ inline float gelu_tanh(float x) {
  float x3 = x * x * x;
  return 0.5f * x * (1.0f + tanhf(0.79788456080286536f * (x + 0.044715f * x3)));
}

// ---------------- prep kernels ----------------
__global__ void zero_int_kernel(int* __restrict__ p, int n) {
  int i = blockIdx.x * 256 + threadIdx.x;
  if (i < n) p[i] = 0;
}

// Wqe[D][h*32+d] = sum_c Wq[D][h*32+c] * We[d][h*32+c]
__global__ void wqe_kernel(const float* __restrict__ Wq, const float* __restrict__ We,
                           float* __restrict__ Wqe) {
  int idx = blockIdx.x * 256 + threadIdx.x;
  if (idx >= 256 * 256) return;
  int D = idx >> 8, col = idx & 255;
  int h = col >> 5, d = col & 31;
  const float* wq = Wq + (size_t)D * 256 + h * 32;
  const float* we = We + (size_t)d * 256 + h * 32;
  float s = 0.f;
#pragma unroll
  for (int c = 0; c < 32; ++c) s += wq[c] * we[c];
  Wqe[idx] = s;
}

// ball = [bq | bk | bv | bqe]
__global__ void ball_kernel(const float* __restrict__ bq, const float* __restrict__ bk,
                            const float* __restrict__ bv, const float* __restrict__ We,
                            float* __restrict__ ball) {
  int j = blockIdx.x * 256 + threadIdx.x;
  if (j >= 1024) return;
  float v;
  if (j < 256) v = bq[j];
  else if (j < 512) v = bk[j - 256];
  else if (j < 768) v = bv[j - 512];
  else {
    int col = j - 768, h = col >> 5, d = col & 31;
    const float* bqh = bq + h * 32;
    const float* we = We + (size_t)d * 256 + h * 32;
    float s = 0.f;
#pragma unroll
    for (int c = 0; c < 32; ++c) s += bqh[c] * we[c];
    v = s;
  }
  ball[j] = v;
}

// WeT[ch][d] = We[d][ch]  (fp32, 256x32)
__global__ void wet_kernel(const float* __restrict__ We, float* __restrict__ WeT) {
  int idx = blockIdx.x * 256 + threadIdx.x;
  if (idx >= 256 * 32) return;
  int ch = idx >> 5, d = idx & 31;
  WeT[idx] = We[(size_t)d * 256 + ch];
}

// Wt[n][k] (bf16) = W[k][n]; 256x256 chunk
__global__ void transpose_w_kernel(const float* __restrict__ W, __bf16* __restrict__ Wt) {
  int idx = blockIdx.x * 256 + threadIdx.x;
  if (idx >= 256 * 256) return;
  int k = idx & 255, n = idx >> 8;
  Wt[idx] = f2bf(W[(size_t)k * 256 + n]);
}

// ---------------- CSR build ----------------
__global__ void count_deg_kernel(const int* __restrict__ dst, int* __restrict__ deg, int E) {
  int e = blockIdx.x * 256 + threadIdx.x;
  if (e < E) atomicAdd(&deg[dst[e]], 1);
}

__global__ __launch_bounds__(1024) void scan_kernel(const int* __restrict__ deg,
                                                    int* __restrict__ offs, int n) {
  __shared__ int part[1024];
  const int tid = threadIdx.x;
  const int per = (n + 1023) / 1024;
  const int base = tid * per;
  int s = 0;
  for (int j = 0; j < per; ++j) {
    int i = base + j;
    if (i < n) s += deg[i];
  }
  part[tid] = s;
  __syncthreads();
  for (int st = 1; st < 1024; st <<= 1) {
    int t = (tid >= st) ? part[tid - st] : 0;
    __syncthreads();
    part[tid] += t;
    __syncthreads();
  }
  int run = (tid > 0) ? part[tid - 1] : 0;
  for (int j = 0; j < per; ++j) {
    int i = base + j;
    if (i < n) { offs[i] = run; run += deg[i]; }
  }
  if (tid == 1023) offs[n] = part[1023];
}

__global__ void scatter_kernel(const int* __restrict__ srcIn, const int* __restrict__ dstIn,
                               const int* __restrict__ offs, int* __restrict__ cursor,
                               int* __restrict__ srcs, int* __restrict__ eids, int E) {
  int e = blockIdx.x * 256 + threadIdx.x;
  if (e >= E) return;
  int d = dstIn[e];
  int p = atomicAdd(&cursor[d], 1);
  int o = offs[d] + p;
  srcs[o] = srcIn[e];
  eids[o] = e;
}

// eaC[o][0..32) = bf16(ea[eids[o]][0..32)) — CSR-ordered edge attrs
__global__ void gather_ea_kernel(const float* __restrict__ ea, const int* __restrict__ eids,
                                 __bf16* __restrict__ eaC, int E) {
  int t = blockIdx.x * 256 + threadIdx.x;
  if (t >= E * 4) return;
  int o = t >> 2, part = t & 3;
  int e = eids[o];
  const float* src = ea + (size_t)e * 32 + part * 8;
  float4v f0 = *(const float4v*)(src);
  float4v f1 = *(const float4v*)(src + 4);
  bf16x8 b;
  b[0] = f2bf(f0[0]); b[1] = f2bf(f0[1]); b[2] = f2bf(f0[2]); b[3] = f2bf(f0[3]);
  b[4] = f2bf(f1[0]); b[5] = f2bf(f1[1]); b[6] = f2bf(f1[2]); b[7] = f2bf(f1[3]);
  *(bf16x8*)(eaC + (size_t)o * 32 + part * 8) = b;
}

// ---------------- MFMA GEMM v2: 128x128 block tile, per-wave 32x128 ----------------
// Y[M][NSTR] = epi(A[M][256] @ W[256][NSTR] + bias); Wt = W^T bf16 [NSTR][256].
// EPI: 0 = (+bias) store bf16; 1 = store fp32; 2 = +bias,gelu, store bf16;
//      3 = +bias,gelu,+resid, store fp32.  PLANES: store bf16 into 4 contiguous
//      [NN][256] planes selected by col>>8 (requires NSTR=1024, EPI=0).
template <int NSTR, bool ABF, int EPI, bool PLANES>
__global__ __launch_bounds__(256) void gemm_k2(
    const float* __restrict__ Af, const __bf16* __restrict__ Abf,
    const __bf16* __restrict__ Wt, const float* __restrict__ bias,
    float* __restrict__ Yf, __bf16* __restrict__ Ybf,
    const float* __restrict__ resid, int M) {
  const int lane = threadIdx.x & 63;
  const int w = threadIdx.x >> 6;
  const int r = lane & 15;
  const int q = lane >> 4;
  const int n0 = blockIdx.x * 128;
  const int mw = blockIdx.y * 128 + w * 32;
  int ar0 = mw + r;      if (ar0 >= M) ar0 = M - 1;
  int ar1 = mw + 16 + r; if (ar1 >= M) ar1 = M - 1;
  const int kq = q * 8;

  float4v acc[2][8];
#pragma unroll
  for (int i = 0; i < 2; ++i)
#pragma unroll
    for (int t = 0; t < 8; ++t) acc[i][t] = (float4v){0.f, 0.f, 0.f, 0.f};

#pragma unroll
  for (int kk = 0; kk < 256; kk += 32) {
    const int ka = kk + kq;
    bf16x8 a0, a1;
    if constexpr (ABF) {
      a0 = *(const bf16x8*)(Abf + (size_t)ar0 * 256 + ka);
      a1 = *(const bf16x8*)(Abf + (size_t)ar1 * 256 + ka);
    } else {
      const float* p0 = Af + (size_t)ar0 * 256 + ka;
      const float* p1 = Af + (size_t)ar1 * 256 + ka;
      float4v f00 = *(const float4v*)(p0), f01 = *(const float4v*)(p0 + 4);
      float4v f10 = *(const float4v*)(p1), f11 = *(const float4v*)(p1 + 4);
#pragma unroll
      for (int j = 0; j < 4; ++j) {
        a0[j] = f2bf(f00[j]); a0[j + 4] = f2bf(f01[j]);
        a1[j] = f2bf(f10[j]); a1[j + 4] = f2bf(f11[j]);
      }
    }
    bf16x8 b[8];
#pragma unroll
    for (int t = 0; t < 8; ++t)
      b[t] = *(const bf16x8*)(Wt + (size_t)(n0 + t * 16 + r) * 256 + ka);
#pragma unroll
    for (int t = 0; t < 8; ++t) {
      acc[0][t] = __builtin_amdgcn_mfma_f32_16x16x32_bf16(a0, b[t], acc[0][t], 0, 0, 0);
      acc[1][t] = __builtin_amdgcn_mfma_f32_16x16x32_bf16(a1, b[t], acc[1][t], 0, 0, 0);
    }
  }

#pragma unroll
  for (int t = 0; t < 8; ++t) {
    const int col = n0 + t * 16 + r;
    const float bb = bias ? bias[col] : 0.0f;
#pragma unroll
    for (int i2 = 0; i2 < 2; ++i2) {
#pragma unroll
      for (int ii = 0; ii < 4; ++ii) {
        const int row = mw + i2 * 16 + q * 4 + ii;
        if (row < M) {
          float v = acc[i2][t][ii] + bb;
          if constexpr (EPI == 2 || EPI == 3) v = gelu_tanh(v);
          if constexpr (PLANES) {
            const int p = col >> 8;
            Ybf[((size_t)p * NN + row) * 256 + (col & 255)] = f2bf(v);
          } else {
            const size_t off = (size_t)row * NSTR + col;
            if constexpr (EPI == 3) v += resid[off];
            if constexpr (EPI == 1 || EPI == 3) Yf[off] = v;
            else Ybf[off] = f2bf(v);
          }
        }
      }
    }
  }
}

// ---------------- attention: one block (4 waves) per dst node ----------------
// Waves split the CSR edge list (stride 4) with online softmax; states merged
// via LDS. Lane owns channels c0=lane*4 (head hg=lane>>3) and edge-dims
// (lane&7)*4 of its head. OUT (fp32, = skip) is RMW'd; AE gets E[ea|alpha] bf16.
__global__ __launch_bounds__(256) void attn_kernel(
    const __bf16* __restrict__ Qp, const __bf16* __restrict__ Kp,
    const __bf16* __restrict__ Vp, const __bf16* __restrict__ Gp,
    const __bf16* __restrict__ eaC,
    const int* __restrict__ offs, const int* __restrict__ srcs,
    float* __restrict__ OUT, __bf16* __restrict__ AE) {
  __shared__ float smx[4][64], sdn[4][64];
  __shared__ float sav[4][64][4], sae[4][64][4];
  const int lane = threadIdx.x & 63;
  const int w = threadIdx.x >> 6;
  const int n = blockIdx.x;
  const int c0 = lane * 4;
  const int sub = lane & 7;

  const bf16x4 q4 = *(const bf16x4*)(Qp + (size_t)n * 256 + c0);
  const bf16x4 g4 = *(const bf16x4*)(Gp + (size_t)n * 256 + c0);
  const float q0 = bf2f(q4[0]), q1 = bf2f(q4[1]), q2 = bf2f(q4[2]), q3 = bf2f(q4[3]);
  const float g0 = bf2f(g4[0]), g1 = bf2f(g4[1]), g2 = bf2f(g4[2]), g3 = bf2f(g4[3]);

  float m = -__builtin_inff();
  float denom = 0.f;
  float4v accv = {0.f, 0.f, 0.f, 0.f};
  float4v acce = {0.f, 0.f, 0.f, 0.f};
  const int beg = offs[n], end = offs[n + 1];
  for (int i = beg + w; i < end; i += 4) {
    const int sn = srcs[i];
    const bf16x4 k4 = *(const bf16x4*)(Kp + (size_t)sn * 256 + c0);
    const bf16x4 v4 = *(const bf16x4*)(Vp + (size_t)sn * 256 + c0);
    const bf16x4 e4 = *(const bf16x4*)(eaC + (size_t)i * 32 + sub * 4);
    const float e0 = bf2f(e4[0]), e1 = bf2f(e4[1]), e2 = bf2f(e4[2]), e3 = bf2f(e4[3]);
    float part = q0 * bf2f(k4[0]) + q1 * bf2f(k4[1]) + q2 * bf2f(k4[2]) + q3 * bf2f(k4[3])
               + g0 * e0 + g1 * e1 + g2 * e2 + g3 * e3;
    part += __shfl_xor(part, 1);
    part += __shfl_xor(part, 2);
    part += __shfl_xor(part, 4);
    const float logit = part * 0.17677669529663687f;  // 1/sqrt(32)
    const float mn = fmaxf(m, logit);
    const float sc = __expf(m - mn);
    const float wt = __expf(logit - mn);
    denom = denom * sc + wt;
    accv[0] = accv[0] * sc + wt * bf2f(v4[0]);
    accv[1] = accv[1] * sc + wt * bf2f(v4[1]);
    accv[2] = accv[2] * sc + wt * bf2f(v4[2]);
    accv[3] = accv[3] * sc + wt * bf2f(v4[3]);
    acce[0] = acce[0] * sc + wt * e0;
    acce[1] = acce[1] * sc + wt * e1;
    acce[2] = acce[2] * sc + wt * e2;
    acce[3] = acce[3] * sc + wt * e3;
    m = mn;
  }
  smx[w][lane] = m;
  sdn[w][lane] = denom;
#pragma unroll
  for (int j = 0; j < 4; ++j) { sav[w][lane][j] = accv[j]; sae[w][lane][j] = acce[j]; }
  __syncthreads();
  if (w == 0) {
    float mstar = smx[0][lane];
#pragma unroll
    for (int ww = 1; ww < 4; ++ww) mstar = fmaxf(mstar, smx[ww][lane]);
    float D = 0.f;
    float4v av = {0.f, 0.f, 0.f, 0.f};
    float4v ae = {0.f, 0.f, 0.f, 0.f};
#pragma unroll
    for (int ww = 0; ww < 4; ++ww) {
      const float dw = sdn[ww][lane];
      if (dw > 0.f) {
        const float sc = __expf(smx[ww][lane] - mstar);
        D += dw * sc;
#pragma unroll
        for (int j = 0; j < 4; ++j) {
          av[j] += sav[ww][lane][j] * sc;
          ae[j] += sae[ww][lane][j] * sc;
        }
      }
    }
    const float inv = 1.0f / (D + 1e-16f);
    float4v o = *(const float4v*)(OUT + (size_t)n * 256 + c0);
#pragma unroll
    for (int j = 0; j < 4; ++j) o[j] += av[j] * inv;
    *(float4v*)(OUT + (size_t)n * 256 + c0) = o;
    bf16x4 aeb;
    aeb[0] = f2bf(ae[0] * inv); aeb[1] = f2bf(ae[1] * inv);
    aeb[2] = f2bf(ae[2] * inv); aeb[3] = f2bf(ae[3] * inv);
    *(bf16x4*)(AE + (size_t)n * 256 + c0) = aeb;
  }
}

// ---------------- post: OUT += (AE @ We) per head ----------------
__global__ __launch_bounds__(256) void post_kernel(
    const __bf16* __restrict__ AE, const float* __restrict__ WeT,
    float* __restrict__ OUT) {
  const int lane = threadIdx.x & 63;
  const int wave = threadIdx.x >> 6;
  const int n = blockIdx.x * 4 + wave;
  const int c0 = lane * 4;
  const int hg = lane >> 3;

  const __bf16* aerow = AE + (size_t)n * HIDDEN + hg * 32;
  float ae[32];
#pragma unroll
  for (int t = 0; t < 4; ++t) {
    bf16x8 a8 = *(const bf16x8*)(aerow + t * 8);
#pragma unroll
    for (int j = 0; j < 8; ++j) ae[t * 8 + j] = bf2f(a8[j]);
  }
  float4v o = *(const float4v*)(OUT + (size_t)n * HIDDEN + c0);
#pragma unroll
  for (int j = 0; j < 4; ++j) {
    const float* wc = WeT + (size_t)(c0 + j) * 32;
    float s = 0.f;
#pragma unroll
    for (int d = 0; d < 32; ++d) s += ae[d] * wc[d];
    o[j] += s;
  }
  *(float4v*)(OUT + (size_t)n * HIDDEN + c0) = o;
}

extern "C" void kernel_launch(void* const* d_in, const int* in_sizes, int n_in,
                              void* d_out, int out_size, void* d_ws, size_t ws_size,
                              hipStream_t stream) {
  (void)in_sizes; (void)n_in; (void)out_size; (void)ws_size;
  const float* x   = (const float*)d_in[0];
  const int*   ei  = (const int*)d_in[1];
  const float* ea  = (const float*)d_in[2];
  const float* Wq  = (const float*)d_in[3];
  const float* bq  = (const float*)d_in[4];
  const float* Wk  = (const float*)d_in[5];
  const float* bk  = (const float*)d_in[6];
  const float* Wv  = (const float*)d_in[7];
  const float* bv  = (const float*)d_in[8];
  const float* We  = (const float*)d_in[9];
  const float* Wsk = (const float*)d_in[10];
  const float* W1  = (const float*)d_in[11];
  const float* b1  = (const float*)d_in[12];
  const float* W2  = (const float*)d_in[13];
  const float* b2  = (const float*)d_in[14];
  float* out = (float*)d_out;

  char* ws = (char*)d_ws;
  size_t off = 0;
  auto alloc = [&](size_t bytes) -> char* {
    off = (off + 255) & ~(size_t)255;
    char* p = ws + off;
    off += bytes;
    return p;
  };
  // ~100 MB total
  __bf16* PL   = (__bf16*)alloc((size_t)4 * NN * 256 * 2);  // Q|K|V|QE planes, 61.44 MB
  __bf16* AE   = (__bf16*)alloc((size_t)NN * 256 * 2);      // 15.36 MB (reused as H1)
  __bf16* eaC  = (__bf16*)alloc((size_t)NE * 32 * 2);       // 19.2 MB
  __bf16* WTall = (__bf16*)alloc((size_t)1024 * 256 * 2);
  __bf16* WTs  = (__bf16*)alloc(256 * 256 * 2);
  __bf16* WT1  = (__bf16*)alloc(256 * 256 * 2);
  __bf16* WT2  = (__bf16*)alloc(256 * 256 * 2);
  float*  Wqe  = (float*)alloc(256 * 256 * 4);
  float*  ball = (float*)alloc(1024 * 4);
  float*  WeT  = (float*)alloc(256 * 32 * 4);
  int* deg    = (int*)alloc((size_t)2 * NN * 4);
  int* cursor = deg + NN;
  int* offs   = (int*)alloc((size_t)(NN + 1) * 4);
  int* srcs   = (int*)alloc((size_t)NE * 4);
  int* eids   = (int*)alloc((size_t)NE * 4);
  __bf16* Qp = PL;
  __bf16* Kp = PL + (size_t)NN * 256;
  __bf16* Vp = PL + (size_t)2 * NN * 256;
  __bf16* Gp = PL + (size_t)3 * NN * 256;
  __bf16* H1 = AE;

  const int* srcIn = ei;       // edge_index[0]
  const int* dstIn = ei + NE;  // edge_index[1]

  // ---- weight prep ----
  wqe_kernel<<<256, 256, 0, stream>>>(Wq, We, Wqe);
  ball_kernel<<<4, 256, 0, stream>>>(bq, bk, bv, We, ball);
  wet_kernel<<<32, 256, 0, stream>>>(We, WeT);
  transpose_w_kernel<<<256, 256, 0, stream>>>(Wq, WTall);
  transpose_w_kernel<<<256, 256, 0, stream>>>(Wk, WTall + 256 * 256);
  transpose_w_kernel<<<256, 256, 0, stream>>>(Wv, WTall + 2 * 256 * 256);
  transpose_w_kernel<<<256, 256, 0, stream>>>(Wqe, WTall + 3 * 256 * 256);
  transpose_w_kernel<<<256, 256, 0, stream>>>(Wsk, WTs);
  transpose_w_kernel<<<256, 256, 0, stream>>>(W1, WT1);
  transpose_w_kernel<<<256, 256, 0, stream>>>(W2, WT2);

  // ---- CSR build + CSR-ordered edge attrs ----
  zero_int_kernel<<<(2 * NN + 255) / 256, 256, 0, stream>>>(deg, 2 * NN);
  count_deg_kernel<<<(NE + 255) / 256, 256, 0, stream>>>(dstIn, deg, NE);
  scan_kernel<<<1, 1024, 0, stream>>>(deg, offs, NN);
  scatter_kernel<<<(NE + 255) / 256, 256, 0, stream>>>(srcIn, dstIn, offs, cursor, srcs, eids, NE);
  gather_ea_kernel<<<(NE * 4 + 255) / 256, 256, 0, stream>>>(ea, eids, eaC, NE);

  const int MB = (NN + 127) / 128;  // 235
  // ---- fused node GEMM -> Q,K,V,QE planes (bf16) ----
  gemm_k2<1024, false, 0, true><<<dim3(8, MB), 256, 0, stream>>>(
      x, nullptr, WTall, ball, nullptr, PL, nullptr, NN);
  // ---- skip GEMM: out = x @ Wskip (fp32) ----
  gemm_k2<256, false, 1, false><<<dim3(2, MB), 256, 0, stream>>>(
      x, nullptr, WTs, nullptr, out, nullptr, nullptr, NN);

  // ---- attention (RMW out, write AE) ----
  attn_kernel<<<NN, 256, 0, stream>>>(Qp, Kp, Vp, Gp, eaC, offs, srcs, out, AE);

  // ---- post: out += AE @ We (per-head) ----
  post_kernel<<<NN / 4, 256, 0, stream>>>(AE, WeT, out);

  // ---- MLP ----
  gemm_k2<256, false, 2, false><<<dim3(2, MB), 256, 0, stream>>>(
      out, nullptr, WT1, b1, nullptr, H1, nullptr, NN);
  gemm_k2<256, true, 3, false><<<dim3(2, MB), 256, 0, stream>>>(
      nullptr, H1, WT2, b2, out, nullptr, out, NN);
}

// Round 4
// 476.865 us; speedup vs baseline: 1.5606x; 1.4817x over previous
//
#include <hip/hip_runtime.h>

#define NN 30000
#define NE 300000
#define HIDDEN 256

typedef __attribute__((ext_vector_type(8))) __bf16 bf16x8;
typedef __attribute__((ext_vector_type(4))) __bf16 bf16x4;
typedef __attribute__((ext_vector_type(4))) float float4v;

__device__ inline __bf16 f2bf(float f) {
  unsigned u = __builtin_bit_cast(unsigned, f);
  u += 0x7fffu + ((u >> 16) & 1u);
  unsigned short s = (unsigned short)(u >> 16);
  return __builtin_bit_cast(__bf16, s);
}
__device__ inline float bf2f(__bf16 b) {
  unsigned short s = __builtin_bit_cast(unsigned short, b);
  unsigned u = ((unsigned)s) << 16;
  return __builtin_bit_cast(float, u);
}
__device__ inline float gelu_tanh(float x) {
  float x3 = x * x * x;
  return 0.5f * x * (1.0f + tanhf(0.79788456080286536f * (x + 0.044715f * x3)));
}

// ---------------- prep kernels ----------------
__global__ void zero_int_kernel(int* __restrict__ p, int n) {
  int i = blockIdx.x * 256 + threadIdx.x;
  if (i < n) p[i] = 0;
}

// x fp32 -> bf16, 8 elems/thread
__global__ void cvt_bf16_kernel(const float* __restrict__ x, __bf16* __restrict__ xb, int n8) {
  int t = blockIdx.x * 256 + threadIdx.x;
  if (t >= n8) return;
  const float* p = x + (size_t)t * 8;
  float4v f0 = *(const float4v*)(p);
  float4v f1 = *(const float4v*)(p + 4);
  bf16x8 b;
#pragma unroll
  for (int j = 0; j < 4; ++j) { b[j] = f2bf(f0[j]); b[j + 4] = f2bf(f1[j]); }
  *(bf16x8*)(xb + (size_t)t * 8) = b;
}

// Wqe[D][h*32+d] = sum_c Wq[D][h*32+c] * We[d][h*32+c]
__global__ void wqe_kernel(const float* __restrict__ Wq, const float* __restrict__ We,
                           float* __restrict__ Wqe) {
  int idx = blockIdx.x * 256 + threadIdx.x;
  if (idx >= 256 * 256) return;
  int D = idx >> 8, col = idx & 255;
  int h = col >> 5, d = col & 31;
  const float* wq = Wq + (size_t)D * 256 + h * 32;
  const float* we = We + (size_t)d * 256 + h * 32;
  float s = 0.f;
#pragma unroll
  for (int c = 0; c < 32; ++c) s += wq[c] * we[c];
  Wqe[idx] = s;
}

// ball = [bq | bk | bv | bqe]
__global__ void ball_kernel(const float* __restrict__ bq, const float* __restrict__ bk,
                            const float* __restrict__ bv, const float* __restrict__ We,
                            float* __restrict__ ball) {
  int j = blockIdx.x * 256 + threadIdx.x;
  if (j >= 1024) return;
  float v;
  if (j < 256) v = bq[j];
  else if (j < 512) v = bk[j - 256];
  else if (j < 768) v = bv[j - 512];
  else {
    int col = j - 768, h = col >> 5, d = col & 31;
    const float* bqh = bq + h * 32;
    const float* we = We + (size_t)d * 256 + h * 32;
    float s = 0.f;
#pragma unroll
    for (int c = 0; c < 32; ++c) s += bqh[c] * we[c];
    v = s;
  }
  ball[j] = v;
}

// WeT[ch][d] = We[d][ch]  (fp32, 256x32)
__global__ void wet_kernel(const float* __restrict__ We, float* __restrict__ WeT) {
  int idx = blockIdx.x * 256 + threadIdx.x;
  if (idx >= 256 * 32) return;
  int ch = idx >> 5, d = idx & 31;
  WeT[idx] = We[(size_t)d * 256 + ch];
}

// Wt[n][k] (bf16) = W[k][n]; 256x256 chunk
__global__ void transpose_w_kernel(const float* __restrict__ W, __bf16* __restrict__ Wt) {
  int idx = blockIdx.x * 256 + threadIdx.x;
  if (idx >= 256 * 256) return;
  int k = idx & 255, n = idx >> 8;
  Wt[idx] = f2bf(W[(size_t)k * 256 + n]);
}

// ---------------- CSR build ----------------
__global__ void count_deg_kernel(const int* __restrict__ dst, int* __restrict__ deg, int E) {
  int e = blockIdx.x * 256 + threadIdx.x;
  if (e < E) atomicAdd(&deg[dst[e]], 1);
}

__global__ __launch_bounds__(1024) void scan_kernel(const int* __restrict__ deg,
                                                    int* __restrict__ offs, int n) {
  __shared__ int part[1024];
  const int tid = threadIdx.x;
  const int per = (n + 1023) / 1024;
  const int base = tid * per;
  int s = 0;
  for (int j = 0; j < per; ++j) {
    int i = base + j;
    if (i < n) s += deg[i];
  }
  part[tid] = s;
  __syncthreads();
  for (int st = 1; st < 1024; st <<= 1) {
    int t = (tid >= st) ? part[tid - st] : 0;
    __syncthreads();
    part[tid] += t;
    __syncthreads();
  }
  int run = (tid > 0) ? part[tid - 1] : 0;
  for (int j = 0; j < per; ++j) {
    int i = base + j;
    if (i < n) { offs[i] = run; run += deg[i]; }
  }
  if (tid == 1023) offs[n] = part[1023];
}

__global__ void scatter_kernel(const int* __restrict__ srcIn, const int* __restrict__ dstIn,
                               const int* __restrict__ offs, int* __restrict__ cursor,
                               int* __restrict__ srcs, int* __restrict__ eids, int E) {
  int e = blockIdx.x * 256 + threadIdx.x;
  if (e >= E) return;
  int d = dstIn[e];
  int p = atomicAdd(&cursor[d], 1);
  int o = offs[d] + p;
  srcs[o] = srcIn[e];
  eids[o] = e;
}

// eaC[o][0..32) = bf16(ea[eids[o]][0..32))
__global__ void gather_ea_kernel(const float* __restrict__ ea, const int* __restrict__ eids,
                                 __bf16* __restrict__ eaC, int E) {
  int t = blockIdx.x * 256 + threadIdx.x;
  if (t >= E * 4) return;
  int o = t >> 2, part = t & 3;
  int e = eids[o];
  const float* src = ea + (size_t)e * 32 + part * 8;
  float4v f0 = *(const float4v*)(src);
  float4v f1 = *(const float4v*)(src + 4);
  bf16x8 b;
#pragma unroll
  for (int j = 0; j < 4; ++j) { b[j] = f2bf(f0[j]); b[j + 4] = f2bf(f1[j]); }
  *(bf16x8*)(eaC + (size_t)o * 32 + part * 8) = b;
}

// ---------------- MFMA GEMM v3 ----------------
// A bf16 [M][256], Wt bf16 [N][256] (N = GX*128). Block = 128 rows x 128 cols,
// per-wave 32x128. Whole B^T tile staged in LDS once (padded stride 264).
// 1D grid, XCD swizzle: bid%8 selects row-stripe so col-blocks sharing A rows
// share an XCD's L2. EPI: 0=+bias bf16; 1=fp32; 2=+bias gelu bf16;
// 3=+bias gelu +resid fp32. PLANES: bf16 into 4 [NN][256] planes by col>>8.
template <int GX, int EPI, bool PLANES>
__global__ __launch_bounds__(256) void gemm_k3(
    const __bf16* __restrict__ A, const __bf16* __restrict__ Wt,
    const float* __restrict__ bias,
    float* __restrict__ Yf, __bf16* __restrict__ Ybf,
    const float* __restrict__ resid, int M, int gyTiles) {
  __shared__ __bf16 Bs[128 * 264];
  const int bid = blockIdx.x;
  const int stripe = bid / (8 * GX);
  const int rem = bid % (8 * GX);
  const int y8 = rem % 8;          // == bid%8 -> XCD id
  const int xt = rem / 8;
  const int y = stripe * 8 + y8;
  if (y >= gyTiles) return;
  const int n0 = xt * 128;

  // stage B^T tile: 128 rows x 256 bf16 -> padded stride 264
  {
    const int t = threadIdx.x;
#pragma unroll
    for (int i = 0; i < 16; ++i) {
      int g = i * 256 + t;       // 4096 chunks of 16B
      int row = g >> 5;
      int c16 = g & 31;
      bf16x8 v = *(const bf16x8*)(Wt + (size_t)(n0 + row) * 256 + c16 * 8);
      *(bf16x8*)(Bs + row * 264 + c16 * 8) = v;
    }
  }
  __syncthreads();

  const int lane = threadIdx.x & 63;
  const int w = threadIdx.x >> 6;
  const int r = lane & 15;
  const int q = lane >> 4;
  const int mw = y * 128 + w * 32;
  int ar0 = mw + r;      if (ar0 >= M) ar0 = M - 1;
  int ar1 = mw + 16 + r; if (ar1 >= M) ar1 = M - 1;
  const int kq = q * 8;

  float4v acc[2][8];
#pragma unroll
  for (int i = 0; i < 2; ++i)
#pragma unroll
    for (int t = 0; t < 8; ++t) acc[i][t] = (float4v){0.f, 0.f, 0.f, 0.f};

#pragma unroll
  for (int kk = 0; kk < 256; kk += 32) {
    const int ka = kk + kq;
    bf16x8 a0 = *(const bf16x8*)(A + (size_t)ar0 * 256 + ka);
    bf16x8 a1 = *(const bf16x8*)(A + (size_t)ar1 * 256 + ka);
    bf16x8 b[8];
#pragma unroll
    for (int t = 0; t < 8; ++t)
      b[t] = *(const bf16x8*)(Bs + (t * 16 + r) * 264 + ka);
#pragma unroll
    for (int t = 0; t < 8; ++t) {
      acc[0][t] = __builtin_amdgcn_mfma_f32_16x16x32_bf16(a0, b[t], acc[0][t], 0, 0, 0);
      acc[1][t] = __builtin_amdgcn_mfma_f32_16x16x32_bf16(a1, b[t], acc[1][t], 0, 0, 0);
    }
  }

  constexpr int NSTR = GX * 128;
#pragma unroll
  for (int t = 0; t < 8; ++t) {
    const int col = n0 + t * 16 + r;
    const float bb = bias ? bias[col] : 0.0f;
#pragma unroll
    for (int i2 = 0; i2 < 2; ++i2) {
#pragma unroll
      for (int ii = 0; ii < 4; ++ii) {
        const int row = mw + i2 * 16 + q * 4 + ii;
        if (row < M) {
          float v = acc[i2][t][ii] + bb;
          if constexpr (EPI == 2 || EPI == 3) v = gelu_tanh(v);
          if constexpr (PLANES) {
            const int p = col >> 8;
            Ybf[((size_t)p * NN + row) * 256 + (col & 255)] = f2bf(v);
          } else {
            const size_t off = (size_t)row * NSTR + col;
            if constexpr (EPI == 3) v += resid[off];
            if constexpr (EPI == 1 || EPI == 3) Yf[off] = v;
            else Ybf[off] = f2bf(v);
          }
        }
      }
    }
  }
}

// ---------------- attention: one block (4 waves) per dst node ----------------
__global__ __launch_bounds__(256) void attn_kernel(
    const __bf16* __restrict__ Qp, const __bf16* __restrict__ Kp,
    const __bf16* __restrict__ Vp, const __bf16* __restrict__ Gp,
    const __bf16* __restrict__ eaC,
    const int* __restrict__ offs, const int* __restrict__ srcs,
    float* __restrict__ OUT, __bf16* __restrict__ AE) {
  __shared__ float smx[4][64], sdn[4][64];
  __shared__ float sav[4][64][4], sae[4][64][4];
  const int lane = threadIdx.x & 63;
  const int w = threadIdx.x >> 6;
  const int n = blockIdx.x;
  const int c0 = lane * 4;
  const int sub = lane & 7;

  const bf16x4 q4 = *(const bf16x4*)(Qp + (size_t)n * 256 + c0);
  const bf16x4 g4 = *(const bf16x4*)(Gp + (size_t)n * 256 + c0);
  const float q0 = bf2f(q4[0]), q1 = bf2f(q4[1]), q2 = bf2f(q4[2]), q3 = bf2f(q4[3]);
  const float g0 = bf2f(g4[0]), g1 = bf2f(g4[1]), g2 = bf2f(g4[2]), g3 = bf2f(g4[3]);

  float m = -__builtin_inff();
  float denom = 0.f;
  float4v accv = {0.f, 0.f, 0.f, 0.f};
  float4v acce = {0.f, 0.f, 0.f, 0.f};
  const int beg = offs[n], end = offs[n + 1];
  for (int i = beg + w; i < end; i += 4) {
    const int sn = srcs[i];
    const bf16x4 k4 = *(const bf16x4*)(Kp + (size_t)sn * 256 + c0);
    const bf16x4 v4 = *(const bf16x4*)(Vp + (size_t)sn * 256 + c0);
    const bf16x4 e4 = *(const bf16x4*)(eaC + (size_t)i * 32 + sub * 4);
    const float e0 = bf2f(e4[0]), e1 = bf2f(e4[1]), e2 = bf2f(e4[2]), e3 = bf2f(e4[3]);
    float part = q0 * bf2f(k4[0]) + q1 * bf2f(k4[1]) + q2 * bf2f(k4[2]) + q3 * bf2f(k4[3])
               + g0 * e0 + g1 * e1 + g2 * e2 + g3 * e3;
    part += __shfl_xor(part, 1);
    part += __shfl_xor(part, 2);
    part += __shfl_xor(part, 4);
    const float logit = part * 0.17677669529663687f;  // 1/sqrt(32)
    const float mn = fmaxf(m, logit);
    const float sc = __expf(m - mn);
    const float wt = __expf(logit - mn);
    denom = denom * sc + wt;
    accv[0] = accv[0] * sc + wt * bf2f(v4[0]);
    accv[1] = accv[1] * sc + wt * bf2f(v4[1]);
    accv[2] = accv[2] * sc + wt * bf2f(v4[2]);
    accv[3] = accv[3] * sc + wt * bf2f(v4[3]);
    acce[0] = acce[0] * sc + wt * e0;
    acce[1] = acce[1] * sc + wt * e1;
    acce[2] = acce[2] * sc + wt * e2;
    acce[3] = acce[3] * sc + wt * e3;
    m = mn;
  }
  smx[w][lane] = m;
  sdn[w][lane] = denom;
#pragma unroll
  for (int j = 0; j < 4; ++j) { sav[w][lane][j] = accv[j]; sae[w][lane][j] = acce[j]; }
  __syncthreads();
  if (w == 0) {
    float mstar = smx[0][lane];
#pragma unroll
    for (int ww = 1; ww < 4; ++ww) mstar = fmaxf(mstar, smx[ww][lane]);
    float D = 0.f;
    float4v av = {0.f, 0.f, 0.f, 0.f};
    float4v ae = {0.f, 0.f, 0.f, 0.f};
#pragma unroll
    for (int ww = 0; ww < 4; ++ww) {
      const float dw = sdn[ww][lane];
      if (dw > 0.f) {
        const float sc = __expf(smx[ww][lane] - mstar);
        D += dw * sc;
#pragma unroll
        for (int j = 0; j < 4; ++j) {
          av[j] += sav[ww][lane][j] * sc;
          ae[j] += sae[ww][lane][j] * sc;
        }
      }
    }
    const float inv = 1.0f / (D + 1e-16f);
    float4v o = *(const float4v*)(OUT + (size_t)n * 256 + c0);
#pragma unroll
    for (int j = 0; j < 4; ++j) o[j] += av[j] * inv;
    *(float4v*)(OUT + (size_t)n * 256 + c0) = o;
    bf16x4 aeb;
    aeb[0] = f2bf(ae[0] * inv); aeb[1] = f2bf(ae[1] * inv);
    aeb[2] = f2bf(ae[2] * inv); aeb[3] = f2bf(ae[3] * inv);
    *(bf16x4*)(AE + (size_t)n * 256 + c0) = aeb;
  }
}

// ---------------- post v2: OUT += AE@We (per-head); OUTh = bf16(OUT) ----------------
// WeT rows held in registers; block processes 64 nodes (4 waves x 16 iters).
__global__ __launch_bounds__(256) void post_kernel(
    const __bf16* __restrict__ AE, const float* __restrict__ WeT,
    float* __restrict__ OUT, __bf16* __restrict__ OUTh) {
  const int lane = threadIdx.x & 63;
  const int wave = threadIdx.x >> 6;
  const int c0 = lane * 4;
  const int hg = lane >> 3;

  float4v w4[4][8];  // lane's 4 WeT rows (c0..c0+3), 32 dims each
#pragma unroll
  for (int j = 0; j < 4; ++j)
#pragma unroll
    for (int s = 0; s < 8; ++s)
      w4[j][s] = *(const float4v*)(WeT + (size_t)(c0 + j) * 32 + s * 4);

  const int nbase = blockIdx.x * 64;
  for (int it = 0; it < 16; ++it) {
    const int n = nbase + it * 4 + wave;
    if (n >= NN) return;
    const __bf16* aerow = AE + (size_t)n * HIDDEN + hg * 32;
    float aef[32];
#pragma unroll
    for (int t = 0; t < 4; ++t) {
      bf16x8 a8 = *(const bf16x8*)(aerow + t * 8);
#pragma unroll
      for (int j = 0; j < 8; ++j) aef[t * 8 + j] = bf2f(a8[j]);
    }
    float4v o = *(const float4v*)(OUT + (size_t)n * HIDDEN + c0);
#pragma unroll
    for (int j = 0; j < 4; ++j) {
      float s = 0.f;
#pragma unroll
      for (int g = 0; g < 8; ++g) {
        s += aef[g * 4 + 0] * w4[j][g][0] + aef[g * 4 + 1] * w4[j][g][1]
           + aef[g * 4 + 2] * w4[j][g][2] + aef[g * 4 + 3] * w4[j][g][3];
      }
      o[j] += s;
    }
    *(float4v*)(OUT + (size_t)n * HIDDEN + c0) = o;
    bf16x4 ob;
    ob[0] = f2bf(o[0]); ob[1] = f2bf(o[1]); ob[2] = f2bf(o[2]); ob[3] = f2bf(o[3]);
    *(bf16x4*)(OUTh + (size_t)n * HIDDEN + c0) = ob;
  }
}

extern "C" void kernel_launch(void* const* d_in, const int* in_sizes, int n_in,
                              void* d_out, int out_size, void* d_ws, size_t ws_size,
                              hipStream_t stream) {
  (void)in_sizes; (void)n_in; (void)out_size; (void)ws_size;
  const float* x   = (const float*)d_in[0];
  const int*   ei  = (const int*)d_in[1];
  const float* ea  = (const float*)d_in[2];
  const float* Wq  = (const float*)d_in[3];
  const float* bq  = (const float*)d_in[4];
  const float* Wk  = (const float*)d_in[5];
  const float* bk  = (const float*)d_in[6];
  const float* Wv  = (const float*)d_in[7];
  const float* bv  = (const float*)d_in[8];
  const float* We  = (const float*)d_in[9];
  const float* Wsk = (const float*)d_in[10];
  const float* W1  = (const float*)d_in[11];
  const float* b1  = (const float*)d_in[12];
  const float* W2  = (const float*)d_in[13];
  const float* b2  = (const float*)d_in[14];
  float* out = (float*)d_out;

  char* ws = (char*)d_ws;
  size_t off = 0;
  auto alloc = [&](size_t bytes) -> char* {
    off = (off + 255) & ~(size_t)255;
    char* p = ws + off;
    off += bytes;
    return p;
  };
  __bf16* PL   = (__bf16*)alloc((size_t)4 * NN * 256 * 2);  // Q|K|V|QE planes
  __bf16* xb   = (__bf16*)alloc((size_t)NN * 256 * 2);
  __bf16* AE   = (__bf16*)alloc((size_t)NN * 256 * 2);      // reused as H1
  __bf16* OUTh = (__bf16*)alloc((size_t)NN * 256 * 2);
  __bf16* eaC  = (__bf16*)alloc((size_t)NE * 32 * 2);
  __bf16* WTall = (__bf16*)alloc((size_t)1024 * 256 * 2);
  __bf16* WTs  = (__bf16*)alloc(256 * 256 * 2);
  __bf16* WT1  = (__bf16*)alloc(256 * 256 * 2);
  __bf16* WT2  = (__bf16*)alloc(256 * 256 * 2);
  float*  Wqe  = (float*)alloc(256 * 256 * 4);
  float*  ball = (float*)alloc(1024 * 4);
  float*  WeT  = (float*)alloc(256 * 32 * 4);
  int* deg    = (int*)alloc((size_t)2 * NN * 4);
  int* cursor = deg + NN;
  int* offs   = (int*)alloc((size_t)(NN + 1) * 4);
  int* srcs   = (int*)alloc((size_t)NE * 4);
  int* eids   = (int*)alloc((size_t)NE * 4);
  __bf16* Qp = PL;
  __bf16* Kp = PL + (size_t)NN * 256;
  __bf16* Vp = PL + (size_t)2 * NN * 256;
  __bf16* Gp = PL + (size_t)3 * NN * 256;
  __bf16* H1 = AE;

  const int* srcIn = ei;       // edge_index[0]
  const int* dstIn = ei + NE;  // edge_index[1]

  // ---- prep ----
  cvt_bf16_kernel<<<(NN * 256 / 8 + 255) / 256, 256, 0, stream>>>(x, xb, NN * 256 / 8);
  wqe_kernel<<<256, 256, 0, stream>>>(Wq, We, Wqe);
  ball_kernel<<<4, 256, 0, stream>>>(bq, bk, bv, We, ball);
  wet_kernel<<<32, 256, 0, stream>>>(We, WeT);
  transpose_w_kernel<<<256, 256, 0, stream>>>(Wq, WTall);
  transpose_w_kernel<<<256, 256, 0, stream>>>(Wk, WTall + 256 * 256);
  transpose_w_kernel<<<256, 256, 0, stream>>>(Wv, WTall + 2 * 256 * 256);
  transpose_w_kernel<<<256, 256, 0, stream>>>(Wqe, WTall + 3 * 256 * 256);
  transpose_w_kernel<<<256, 256, 0, stream>>>(Wsk, WTs);
  transpose_w_kernel<<<256, 256, 0, stream>>>(W1, WT1);
  transpose_w_kernel<<<256, 256, 0, stream>>>(W2, WT2);

  // ---- CSR build + CSR-ordered edge attrs ----
  zero_int_kernel<<<(2 * NN + 255) / 256, 256, 0, stream>>>(deg, 2 * NN);
  count_deg_kernel<<<(NE + 255) / 256, 256, 0, stream>>>(dstIn, deg, NE);
  scan_kernel<<<1, 1024, 0, stream>>>(deg, offs, NN);
  scatter_kernel<<<(NE + 255) / 256, 256, 0, stream>>>(srcIn, dstIn, offs, cursor, srcs, eids, NE);
  gather_ea_kernel<<<(NE * 4 + 255) / 256, 256, 0, stream>>>(ea, eids, eaC, NE);

  const int gy = (NN + 127) / 128;          // 235
  const int stripes = (gy + 7) / 8;         // 30
  // ---- fused node GEMM -> Q,K,V,QE planes ----
  gemm_k3<8, 0, true><<<stripes * 64, 256, 0, stream>>>(
      xb, WTall, ball, nullptr, PL, nullptr, NN, gy);
  // ---- skip GEMM: out = x @ Wskip (fp32) ----
  gemm_k3<2, 1, false><<<stripes * 16, 256, 0, stream>>>(
      xb, WTs, nullptr, out, nullptr, nullptr, NN, gy);

  // ---- attention (RMW out, write AE) ----
  attn_kernel<<<NN, 256, 0, stream>>>(Qp, Kp, Vp, Gp, eaC, offs, srcs, out, AE);

  // ---- post: out += AE @ We (per-head), OUTh = bf16(out) ----
  post_kernel<<<(NN + 63) / 64, 256, 0, stream>>>(AE, WeT, out, OUTh);

  // ---- MLP ----
  gemm_k3<2, 2, false><<<stripes * 16, 256, 0, stream>>>(
      OUTh, WT1, b1, nullptr, H1, nullptr, NN, gy);
  gemm_k3<2, 3, false><<<stripes * 16, 256, 0, stream>>>(
      H1, WT2, b2, out, nullptr, out, NN, gy);
}